// Round 6
// baseline (498.872 us; speedup 1.0000x reference)
//
#include <hip/hip_runtime.h>
#include <hip/hip_bf16.h>

__device__ __forceinline__ float lrelu02(float v) { return v > 0.f ? v : 0.2f * v; }

// manual bf16 <-> f32 (RNE); finite data only
__device__ __forceinline__ float bf2f(unsigned short u) {
    union { unsigned int i; float f; } v; v.i = ((unsigned int)u) << 16; return v.f;
}
__device__ __forceinline__ unsigned short f2bf(float f) {
    union { float f; unsigned int i; } v; v.f = f;
    unsigned int x = v.i;
    return (unsigned short)((x + 0x7fffu + ((x >> 16) & 1u)) >> 16);
}
// packed-pair bf16 extract
__device__ __forceinline__ float blo(unsigned int u) {
    union { unsigned int i; float f; } v; v.i = u << 16; return v.f;
}
__device__ __forceinline__ float bhi(unsigned int u) {
    union { unsigned int i; float f; } v; v.i = u & 0xffff0000u; return v.f;
}

typedef float f32x4 __attribute__((ext_vector_type(4)));
typedef short s16x8 __attribute__((ext_vector_type(8)));

// ---------- fused: CSR rank pass + layer-1 dense via MFMA ----------
// (r5: MFMA rewrite verified — absmax held 0.0039, gemm1 off the top-5.)
__global__ __launch_bounds__(512) void gemm1_k(
    const float* __restrict__ x, const float* __restrict__ W1,
    const float* __restrict__ aw_s, const float* __restrict__ aw_d,
    unsigned short* __restrict__ h1b, float* __restrict__ as1, float* __restrict__ ad1, int N,
    const int* __restrict__ ei, int E, int* __restrict__ deg, int* __restrict__ rank)
{
    // --- rank slice (grid-stride over E+N edges); overlaps with W staging + MFMA ---
    {
        const int total = E + N;
        const int stride = gridDim.x * 512;
        for (int e = blockIdx.x * 512 + threadIdx.x; e < total; e += stride) {
            int d = (e < E) ? ei[E + e] : (e - E);
            rank[e] = atomicAdd(&deg[d], 1);
        }
    }

    // --- stage W1 transposed as bf16: Wt[col][k ^ ((col&7)<<3)] ---
    __shared__ unsigned short Wt[128 * 128];   // 32 KB
    {
        const float4* W4 = (const float4*)W1;
        for (int i = threadIdx.x; i < 128 * 32; i += 512) {
            float4 f = W4[i];                      // row k = i>>5, cols 4t..4t+3
            int k = i >> 5, c4 = (i & 31) * 4;
            #pragma unroll
            for (int j = 0; j < 4; ++j) {
                int col = c4 + j;
                float fv = j == 0 ? f.x : j == 1 ? f.y : j == 2 ? f.z : f.w;
                Wt[col * 128 + (k ^ ((col & 7) << 3))] = f2bf(fv);
            }
        }
    }

    const int lane = threadIdx.x & 63;
    const int wv   = threadIdx.x >> 6;          // 0..7
    const int li   = lane & 15;                 // M-row (A) / N-col (B,D) index
    const int kg   = lane >> 4;                 // k-subchunk 0..3
    const int row0 = blockIdx.x * 128 + wv * 16;

    const int rc = (row0 + li < N) ? (row0 + li) : (N - 1);   // clamped A row
    const float4* xr = (const float4*)(x + (size_t)rc * 128);

    f32x4 acc[8];
    #pragma unroll
    for (int ct = 0; ct < 8; ++ct) acc[ct] = {0.f, 0.f, 0.f, 0.f};

    __syncthreads();

    #pragma unroll
    for (int ks = 0; ks < 4; ++ks) {
        // A fragment: x[rc][ks*32 + kg*8 .. +7] as hi/lo bf16 split
        float4 f0 = xr[ks * 8 + kg * 2];
        float4 f1 = xr[ks * 8 + kg * 2 + 1];
        float xf[8] = {f0.x, f0.y, f0.z, f0.w, f1.x, f1.y, f1.z, f1.w};
        s16x8 ahi, alo;
        #pragma unroll
        for (int j = 0; j < 8; ++j) {
            unsigned short h = f2bf(xf[j]);
            ahi[j] = (short)h;
            alo[j] = (short)f2bf(xf[j] - bf2f(h));
        }
        const int kbase = ks * 32 + kg * 8;
        #pragma unroll
        for (int ct = 0; ct < 8; ++ct) {
            const int col = ct * 16 + li;
            const s16x8 b = *reinterpret_cast<const s16x8*>(
                Wt + col * 128 + (kbase ^ ((col & 7) << 3)));
            acc[ct] = __builtin_amdgcn_mfma_f32_16x16x32_bf16(ahi, b, acc[ct], 0, 0, 0);
            acc[ct] = __builtin_amdgcn_mfma_f32_16x16x32_bf16(alo, b, acc[ct], 0, 0, 0);
        }
    }

    // --- epilogue: attn dots + bf16 h1 write ---
    float aws_[8], awd_[8];
    #pragma unroll
    for (int t = 0; t < 8; ++t) { aws_[t] = aw_s[t * 16 + li]; awd_[t] = aw_d[t * 16 + li]; }

    #pragma unroll
    for (int i = 0; i < 4; ++i) {
        const int gr = row0 + (lane >> 4) * 4 + i;
        const bool valid = gr < N;
        float s0 = acc[0][i] * aws_[0] + acc[1][i] * aws_[1];
        float s1 = acc[2][i] * aws_[2] + acc[3][i] * aws_[3];
        float s2 = acc[4][i] * aws_[4] + acc[5][i] * aws_[5];
        float s3 = acc[6][i] * aws_[6] + acc[7][i] * aws_[7];
        float d0 = acc[0][i] * awd_[0] + acc[1][i] * awd_[1];
        float d1 = acc[2][i] * awd_[2] + acc[3][i] * awd_[3];
        float d2 = acc[4][i] * awd_[4] + acc[5][i] * awd_[5];
        float d3 = acc[6][i] * awd_[6] + acc[7][i] * awd_[7];
        #pragma unroll
        for (int m = 1; m < 16; m <<= 1) {
            s0 += __shfl_xor(s0, m, 16); s1 += __shfl_xor(s1, m, 16);
            s2 += __shfl_xor(s2, m, 16); s3 += __shfl_xor(s3, m, 16);
            d0 += __shfl_xor(d0, m, 16); d1 += __shfl_xor(d1, m, 16);
            d2 += __shfl_xor(d2, m, 16); d3 += __shfl_xor(d3, m, 16);
        }
        if (valid) {
            if (li < 4) {
                float sv = li == 0 ? s0 : li == 1 ? s1 : li == 2 ? s2 : s3;
                float dv = li == 0 ? d0 : li == 1 ? d1 : li == 2 ? d2 : d3;
                as1[gr * 4 + li] = sv;
                ad1[gr * 4 + li] = dv;
            }
            #pragma unroll
            for (int ct = 0; ct < 8; ++ct)
                h1b[(size_t)gr * 128 + ct * 16 + li] = f2bf(acc[ct][i]);
        }
    }
}

// ---------- CSR scan ----------
__global__ __launch_bounds__(256) void blocksum_k(
    const int* __restrict__ deg, int N, int* __restrict__ bsum)
{
    __shared__ int sh[256];
    int i = blockIdx.x * 256 + threadIdx.x;
    sh[threadIdx.x] = (i < N) ? deg[i] : 0;
    __syncthreads();
    for (int off = 128; off; off >>= 1) {
        if (threadIdx.x < off) sh[threadIdx.x] += sh[threadIdx.x + off];
        __syncthreads();
    }
    if (threadIdx.x == 0) bsum[blockIdx.x] = sh[0];
}

__global__ __launch_bounds__(1024) void scanbsum_k(int* __restrict__ bsum, int nb)
{
    __shared__ int buf[1024];
    __shared__ int carry;
    if (threadIdx.x == 0) carry = 0;
    __syncthreads();
    for (int base = 0; base < nb; base += 1024) {
        int i = base + threadIdx.x;
        int v = (i < nb) ? bsum[i] : 0;
        buf[threadIdx.x] = v;
        __syncthreads();
        for (int off = 1; off < 1024; off <<= 1) {
            int t = (threadIdx.x >= off) ? buf[threadIdx.x - off] : 0;
            __syncthreads();
            buf[threadIdx.x] += t;
            __syncthreads();
        }
        if (i < nb) bsum[i] = buf[threadIdx.x] - v + carry;   // exclusive
        __syncthreads();
        if (threadIdx.x == 0) carry += buf[1023];
        __syncthreads();
    }
}

__global__ __launch_bounds__(256) void rowptr_k(
    const int* __restrict__ deg, const int* __restrict__ bsum, int N, int E,
    int* __restrict__ rowptr)
{
    __shared__ int buf[256];
    int i = blockIdx.x * 256 + threadIdx.x;
    int v = (i < N) ? deg[i] : 0;
    buf[threadIdx.x] = v;
    __syncthreads();
    for (int off = 1; off < 256; off <<= 1) {
        int t = (threadIdx.x >= off) ? buf[threadIdx.x - off] : 0;
        __syncthreads();
        buf[threadIdx.x] += t;
        __syncthreads();
    }
    if (i < N) rowptr[i] = bsum[blockIdx.x] + buf[threadIdx.x] - v;
    if (i == 0) rowptr[N] = E + N;
}

// Pure scatter, no atomic (rank already known).
__global__ __launch_bounds__(256) void place_k(
    const int* __restrict__ ei, int E, int N,
    const int* __restrict__ rank, const int* __restrict__ rowptr,
    int* __restrict__ csr)
{
    int e = blockIdx.x * 256 + threadIdx.x;
    if (e >= E + N) return;
    int s, d;
    if (e < E) { s = ei[e]; d = ei[E + e]; } else { s = d = e - E; }
    csr[rowptr[d] + rank[e]] = s;
}

// ---------- layer-1 fused: softmax-aggregate + bias + ELU + gemm2 + attn2 dots ----------
// r5 post-mortem: old layout ran a SERIAL 16-iteration readlane+bpermute broadcast per
// chunk (~17 serial iters per dst) -> latency-bound at 112us (VALU 48%, HBM 28%, neither
// saturated). gat2_k's group-per-edge layout is measurably cheaper on the same graph.
// Rewrite mirrors it: 4 edges concurrently, one 16-lane group per edge. Group g loads
// src id + as1 float4 (uniform within group), computes all 4 head weights per-lane
// (4 exps wave-wide = 1/edge-slot), reads its row in 4 quarter-row passes (lane t covers
// cols {i*32+t*2,+1}, weight w[i]). No per-edge readlane/bpermute; 4-edge steps are
// independent -> deep row-gather MLP. Cross-group acc/den reduce (xor 16/32) once in
// the epilogue; gemm2 p-reduce is within-group only (groups identical post-reduce).
__global__ __launch_bounds__(256) void gat1_k(
    const int* __restrict__ csr, const int* __restrict__ rowptr,
    const float* __restrict__ as1, const float* __restrict__ ad1,
    const unsigned short* __restrict__ h1b, const float* __restrict__ b1,
    const float* __restrict__ W2, const float* __restrict__ aw_s2, const float* __restrict__ aw_d2,
    float* __restrict__ g, float* __restrict__ as2, float* __restrict__ ad2, int N)
{
    const int wid  = (blockIdx.x * 256 + threadIdx.x) >> 6;
    const int lane = threadIdx.x & 63;
    if (wid >= N) return;
    const int start = rowptr[wid], end = rowptr[wid + 1];
    const int grp = lane >> 4;      // edge slot 0..3
    const int t   = lane & 15;      // quarter-row col index

    // dst-side per-head terms (every lane holds all 4 heads)
    const float4 ad4 = *(const float4*)(ad1 + (size_t)wid * 4);
    const float4 at4 = *(const float4*)(as1 + (size_t)wid * 4);
    const float mh0 = lrelu02(at4.x + ad4.x);
    const float mh1 = lrelu02(at4.y + ad4.y);
    const float mh2 = lrelu02(at4.z + ad4.z);
    const float mh3 = lrelu02(at4.w + ad4.w);

    float den0 = 0.f, den1 = 0.f, den2 = 0.f, den3 = 0.f;
    float acc[4][2];
    #pragma unroll
    for (int i = 0; i < 4; ++i) { acc[i][0] = 0.f; acc[i][1] = 0.f; }

    for (int k = start; k < end; k += 4) {
        const int idx = k + grp;
        const bool valid = idx < end;
        const int s = valid ? csr[idx] : wid;
        const float4 a4 = *(const float4*)(as1 + (size_t)s * 4);
        float w0 = valid ? __expf(lrelu02(a4.x + ad4.x) - mh0) : 0.f;
        float w1 = valid ? __expf(lrelu02(a4.y + ad4.y) - mh1) : 0.f;
        float w2 = valid ? __expf(lrelu02(a4.z + ad4.z) - mh2) : 0.f;
        float w3 = valid ? __expf(lrelu02(a4.w + ad4.w) - mh3) : 0.f;
        den0 += w0; den1 += w1; den2 += w2; den3 += w3;
        const unsigned short* hr = h1b + (size_t)s * 128 + t * 2;
        #pragma unroll
        for (int i = 0; i < 4; ++i) {
            const unsigned int pv = *(const unsigned int*)(hr + i * 32);
            const float wi = i == 0 ? w0 : i == 1 ? w1 : i == 2 ? w2 : w3;
            acc[i][0] = fmaf(wi, blo(pv), acc[i][0]);
            acc[i][1] = fmaf(wi, bhi(pv), acc[i][1]);
        }
    }

    // cross-group reduce (groups processed disjoint edge subsets)
    den0 += __shfl_xor(den0, 16); den0 += __shfl_xor(den0, 32);
    den1 += __shfl_xor(den1, 16); den1 += __shfl_xor(den1, 32);
    den2 += __shfl_xor(den2, 16); den2 += __shfl_xor(den2, 32);
    den3 += __shfl_xor(den3, 16); den3 += __shfl_xor(den3, 32);
    #pragma unroll
    for (int i = 0; i < 4; ++i) {
        acc[i][0] += __shfl_xor(acc[i][0], 16); acc[i][0] += __shfl_xor(acc[i][0], 32);
        acc[i][1] += __shfl_xor(acc[i][1], 16); acc[i][1] += __shfl_xor(acc[i][1], 32);
    }

    const float rd0 = 1.f / (den0 + 1e-16f);
    const float rd1 = 1.f / (den1 + 1e-16f);
    const float rd2 = 1.f / (den2 + 1e-16f);
    const float rd3 = 1.f / (den3 + 1e-16f);

    // bias + ELU; lane holds cols {i*32 + t*2, +1}
    float v[4][2];
    #pragma unroll
    for (int i = 0; i < 4; ++i) {
        const int c = i * 32 + t * 2;
        const float rdi = i == 0 ? rd0 : i == 1 ? rd1 : i == 2 ? rd2 : rd3;
        float v0 = acc[i][0] * rdi + b1[c];
        float v1 = acc[i][1] * rdi + b1[c + 1];
        v[i][0] = v0 > 0.f ? v0 : expm1f(v0);
        v[i][1] = v1 > 0.f ? v1 : expm1f(v1);
    }

    // fused gemm2: p_j = sum over this lane's 8 cols of elu * W2[col][j]
    float p0 = 0.f, p1 = 0.f, p2 = 0.f, p3 = 0.f, p4 = 0.f, p5 = 0.f, p6 = 0.f, p7 = 0.f;
    #pragma unroll
    for (int i = 0; i < 4; ++i) {
        const int c = i * 32 + t * 2;
        const float4 wa = *(const float4*)(W2 + c * 8);
        const float4 wb = *(const float4*)(W2 + c * 8 + 4);
        const float4 wc = *(const float4*)(W2 + c * 8 + 8);
        const float4 wd = *(const float4*)(W2 + c * 8 + 12);
        p0 += v[i][0] * wa.x + v[i][1] * wc.x;
        p1 += v[i][0] * wa.y + v[i][1] * wc.y;
        p2 += v[i][0] * wa.z + v[i][1] * wc.z;
        p3 += v[i][0] * wa.w + v[i][1] * wc.w;
        p4 += v[i][0] * wb.x + v[i][1] * wd.x;
        p5 += v[i][0] * wb.y + v[i][1] * wd.y;
        p6 += v[i][0] * wb.z + v[i][1] * wd.z;
        p7 += v[i][0] * wb.w + v[i][1] * wd.w;
    }
    // reduce within group only (t = 0..15): groups hold identical values post acc-reduce
    #pragma unroll
    for (int m = 1; m < 16; m <<= 1) {
        p0 += __shfl_xor(p0, m, 16); p1 += __shfl_xor(p1, m, 16);
        p2 += __shfl_xor(p2, m, 16); p3 += __shfl_xor(p3, m, 16);
        p4 += __shfl_xor(p4, m, 16); p5 += __shfl_xor(p5, m, 16);
        p6 += __shfl_xor(p6, m, 16); p7 += __shfl_xor(p7, m, 16);
    }

    if (lane == 0) {
        float4 g0 = {p0, p1, p2, p3};
        float4 g1 = {p4, p5, p6, p7};
        *(float4*)(g + (size_t)wid * 8)     = g0;
        *(float4*)(g + (size_t)wid * 8 + 4) = g1;
        const float4 s0 = *(const float4*)(aw_s2);
        const float4 s1 = *(const float4*)(aw_s2 + 4);
        const float4 d0 = *(const float4*)(aw_d2);
        const float4 d1 = *(const float4*)(aw_d2 + 4);
        as2[wid] = p0 * s0.x + p1 * s0.y + p2 * s0.z + p3 * s0.w
                 + p4 * s1.x + p5 * s1.y + p6 * s1.z + p7 * s1.w;
        ad2[wid] = p0 * d0.x + p1 * d0.y + p2 * d0.z + p3 * d0.w
                 + p4 * d1.x + p5 * d1.y + p6 * d1.z + p7 * d1.w;
    }
}

// ---------- layer-2 single-pass softmax+aggregate+epilogue: one wave per dst ----------
__global__ __launch_bounds__(256) void gat2_k(
    const int* __restrict__ csr, const int* __restrict__ rowptr,
    const float* __restrict__ as2, const float* __restrict__ ad2,
    const float* __restrict__ g, const float* __restrict__ b2_,
    const float* __restrict__ Wlin, const float* __restrict__ blin,
    float* __restrict__ out, int N)
{
    const int wid  = (blockIdx.x * 256 + threadIdx.x) >> 6;
    const int lane = threadIdx.x & 63;
    if (wid >= N) return;
    const int start = rowptr[wid], end = rowptr[wid + 1];
    const int i8  = lane & 7;
    const int grp = lane >> 3;
    const float adh = ad2[wid];
    const float mh  = lrelu02(as2[wid] + adh);
    float den = 0.f, acc = 0.f;
    int k0 = start;
    for (; k0 + 8 <= end; k0 += 8) {
        int s = csr[k0 + i8];
        float w = __expf(lrelu02(as2[s] + adh) - mh);
        den += w;
        int   se = __shfl(s, grp, 8);
        float we = __shfl(w, grp, 8);
        acc = fmaf(we, g[(size_t)se * 8 + i8], acc);
    }
    int cnt = end - k0;
    if (cnt > 0) {
        int s = (i8 < cnt) ? csr[k0 + i8] : wid;
        float w = (i8 < cnt) ? __expf(lrelu02(as2[s] + adh) - mh) : 0.f;
        den += w;
        int   se = __shfl(s, grp, 8);
        float we = __shfl(w, grp, 8);
        acc = fmaf(we, g[(size_t)se * 8 + i8], acc);
    }
    den += __shfl_xor(den, 1); den += __shfl_xor(den, 2); den += __shfl_xor(den, 4);
    acc += __shfl_xor(acc, 8); acc += __shfl_xor(acc, 16); acc += __shfl_xor(acc, 32);
    float v = acc / (den + 1e-16f) + b2_[i8];
    v = v > 0.f ? v : expm1f(v);
    float t = v * Wlin[i8];
    t += __shfl_xor(t, 1); t += __shfl_xor(t, 2); t += __shfl_xor(t, 4);
    if (lane == 0) out[wid] = 1.f / (1.f + __expf(-(t + blin[0])));
}

extern "C" void kernel_launch(void* const* d_in, const int* in_sizes, int n_in,
                              void* d_out, int out_size, void* d_ws, size_t ws_size,
                              hipStream_t stream)
{
    (void)n_in; (void)out_size; (void)ws_size;
    const float* x    = (const float*)d_in[0];
    const int*   ei   = (const int*)d_in[1];
    // d_in[2] = edge_attr, ignored
    const float* W1   = (const float*)d_in[3];
    const float* as1w = (const float*)d_in[4];
    const float* ad1w = (const float*)d_in[5];
    const float* b1   = (const float*)d_in[6];
    const float* W2   = (const float*)d_in[7];
    const float* as2w = (const float*)d_in[8];
    const float* ad2w = (const float*)d_in[9];
    const float* b2v  = (const float*)d_in[10];
    const float* Wlin = (const float*)d_in[11];
    const float* blin = (const float*)d_in[12];

    const int N = in_sizes[0] / 128;
    const int E = in_sizes[1] / 2;
    const int total = E + N;

    // workspace layout
    float* p = (float*)d_ws;
    unsigned short* h1b = (unsigned short*)p; p += (size_t)N * 64;  // N*128 bf16
    float* as1  = p; p += (size_t)N * 4;
    float* ad1  = p; p += (size_t)N * 4;
    float* g    = p; p += (size_t)N * 8;
    float* as2  = p; p += (size_t)N;
    float* ad2  = p; p += (size_t)N;
    int* deg    = (int*)p; p += (size_t)N;
    int* rowptr = (int*)p; p += (size_t)N + 1;
    int* bsum   = (int*)p; p += ((size_t)N + 255) / 256;
    int* rank   = (int*)p; p += (size_t)total;
    int* csr    = (int*)p; p += (size_t)total;

    const int eb = (total + 255) / 256;
    const int nb = (N + 255) / 256;

    hipMemsetAsync(deg, 0, (size_t)N * sizeof(int), stream);
    // fused: rank pass + layer-1 GEMM on the matrix pipe (MFMA bf16 hi/lo split)
    gemm1_k<<<(N + 127) / 128, 512, 0, stream>>>(x, W1, as1w, ad1w, h1b, as1, ad1, N,
                                                 ei, E, deg, rank);
    blocksum_k<<<nb, 256, 0, stream>>>(deg, N, bsum);
    scanbsum_k<<<1, 1024, 0, stream>>>(bsum, nb);
    rowptr_k<<<nb, 256, 0, stream>>>(deg, bsum, N, E, rowptr);
    place_k<<<eb, 256, 0, stream>>>(ei, E, N, rank, rowptr, csr);

    // layer 1: softmax + aggregate + bias + ELU + gemm2 + attn2 dots (fused, group-per-edge)
    gat1_k<<<(N * 64 + 255) / 256, 256, 0, stream>>>(csr, rowptr, as1, ad1, h1b, b1,
                                                     W2, as2w, ad2w, g, as2, ad2, N);
    // layer 2 + epilogue
    gat2_k<<<(N * 64 + 255) / 256, 256, 0, stream>>>(csr, rowptr, as2, ad2, g, b2v, Wlin, blin,
                                                     (float*)d_out, N);
}